// Round 1
// baseline (301.317 us; speedup 1.0000x reference)
//
#include <hip/hip_runtime.h>
#include <hip/hip_fp16.h>

typedef _Float16 half8 __attribute__((ext_vector_type(8)));
typedef float floatx4 __attribute__((ext_vector_type(4)));

// wperm layout: hi part at [0, 6*512*512), lo part at [WLO_OFF, 2*WLO_OFF)
#define WLO_OFF (6 * 512 * 512)
#define WMAT_STRIDE ((size_t)(8 * 16 * 2048))  // halfs per W matrix in wperm

// ---------------------------------------------------------------------------
// P1: convert 6 W matrices [512(k) x 512(n)] fp32 -> fp16 hi + fp16 lo
// (lo = fp16(W - float(hi)), ~22-bit effective mantissa), laid out in MFMA
// B-operand fragment order: tile(w, nt, ki) is 4096B; within tile, chunk
// (u, l) at u*1024 + l*16 holds B[k0 + 8*(l>>4) + j][n0 + 16*u + (l&15)],
// j = 0..7 contiguous.
// ---------------------------------------------------------------------------
__global__ __launch_bounds__(256) void permute_w(
    const float* __restrict__ Wir, const float* __restrict__ Whr,
    const float* __restrict__ Wiz, const float* __restrict__ Whz,
    const float* __restrict__ Win, const float* __restrict__ Whn,
    _Float16* __restrict__ wperm) {
  __shared__ __align__(16) float tile[32 * 68];  // padded rows
  const int b = blockIdx.x;
  const int w = b >> 7;         // 0..5
  const int rem = b & 127;
  const int ki = rem >> 3;      // 0..15 (k-tile)
  const int nt = rem & 7;       // 0..7  (n-tile of 64)
  const float* W = (w == 0) ? Wir : (w == 1) ? Whr : (w == 2) ? Wiz
                 : (w == 3) ? Whz : (w == 4) ? Win : Whn;
  const int k0 = ki * 32, n0 = nt * 64;
  const int t = threadIdx.x;

  // coalesced read: thread t reads W[k0 + (t>>3)][n0 + (t&7)*8 .. +7]
  const int kk = t >> 3;
  const int nn = (t & 7) * 8;
  const float* src = W + (k0 + kk) * 512 + n0 + nn;
  float4 f0 = *(const float4*)(src);
  float4 f1 = *(const float4*)(src + 4);
  float* drow = tile + kk * 68 + nn;
  *(float4*)(drow) = f0;
  *(float4*)(drow + 4) = f1;
  __syncthreads();

  // gather fragment chunk c = t: u = t>>6, l = t&63
  const int u = t >> 6, l = t & 63;
  const int nloc = 16 * u + (l & 15);
  const int kbase = 8 * (l >> 4);
  half8 vh, vl;
#pragma unroll
  for (int j = 0; j < 8; ++j) {
    float f = tile[(kbase + j) * 68 + nloc];
    _Float16 hi = (_Float16)f;
    _Float16 lo = (_Float16)(f - (float)hi);
    vh[j] = hi;
    vl[j] = lo;
  }
  const size_t off = ((size_t)((w * 8 + nt) * 16 + ki)) * 2048 + t * 8;
  *(half8*)(wperm + off) = vh;
  *(half8*)(wperm + WLO_OFF + off) = vl;
}

// ---------------------------------------------------------------------------
// Fused GRU with fp16 hi/lo emulated-fp32 MFMA:
//   a*b ~= a_hi*b_hi + a_lo*b_hi + a_hi*b_lo   (residual ~2^-22)
// Block tile 128(m) x 64(n), 4 waves of 64x32, BK=32, K=512.
//
// Schedule (this round): SINGLE barrier per k-step, double-buffered x/h LDS.
//   - W_hi AND W_lo fragments read direct from global (fragment-ordered,
//     16B/lane coalesced, L2-resident per XCD thanks to nt = bid&7 swizzle).
//     No global_load_lds -> no forced vmcnt(0)-heavy barrier drain.
//   - next k-step's x/h fp32 loads ISSUED before the MFMA cluster; the
//     hi/lo split (VALU) + ds_writes happen AFTER the MFMAs; one barrier.
//     HBM latency and split VALU hide under 144 MFMAs/wave/k-step.
// ---------------------------------------------------------------------------
__global__ __launch_bounds__(256, 2) void gru_fused(
    const float* __restrict__ x, const float* __restrict__ h,
    const _Float16* __restrict__ wperm,
    const float* __restrict__ br, const float* __restrict__ bz,
    const float* __restrict__ bn, float* __restrict__ out) {
  // 64 KB double-buffered A staging: [buf][Xh|Xl|Hh|Hl][4096 halfs]
  __shared__ __align__(16) _Float16 ldsA[2 * 4 * 4096];

  const int t = threadIdx.x;
  const int lane = t & 63;
  const int wv = t >> 6;
  const int wm = wv >> 1;  // 0..1: wave row block of 64
  const int wn = wv & 1;   // 0..1: wave col block of 32
  const int bid = blockIdx.x;
  const int nt = bid & 7;   // n-tile -> aligns with round-robin XCD for W L2 locality
  const int mt = bid >> 3;
  const int m0 = mt * 128;
  const int n0 = nt * 64;
  const _Float16* wlo = wperm + WLO_OFF;

  floatx4 acc_r[4][2] = {};
  floatx4 acc_z[4][2] = {};
  floatx4 acc_in[4][2] = {};
  floatx4 acc_hn[4][2] = {};

  // staging chunks: c in {t, t+256}; s=c>>6, l=c&63,
  // row m = 16s + (l&15), k offset = 8*(l>>4). Chunk written at base + c*8.
  const int c1 = t + 256;
  const int mA0 = 16 * (t >> 6) + (t & 15);
  const int kA0 = 8 * ((t & 63) >> 4);
  const int mA1 = 16 * (c1 >> 6) + (c1 & 15);
  const int kA1 = 8 * ((c1 & 63) >> 4);

  const float* px0 = x + (m0 + mA0) * 512 + kA0;
  const float* px1 = x + (m0 + mA1) * 512 + kA1;
  const float* ph0 = h + (m0 + mA0) * 512 + kA0;
  const float* ph1 = h + (m0 + mA1) * 512 + kA1;

  // ---- prologue: stage k-tile 0 into buffer 0 ----
  {
    float v[4][8];
    *(float4*)&v[0][0] = *(const float4*)(px0);
    *(float4*)&v[0][4] = *(const float4*)(px0 + 4);
    *(float4*)&v[1][0] = *(const float4*)(px1);
    *(float4*)&v[1][4] = *(const float4*)(px1 + 4);
    *(float4*)&v[2][0] = *(const float4*)(ph0);
    *(float4*)&v[2][4] = *(const float4*)(ph0 + 4);
    *(float4*)&v[3][0] = *(const float4*)(ph1);
    *(float4*)&v[3][4] = *(const float4*)(ph1 + 4);
#pragma unroll
    for (int g = 0; g < 4; ++g) {
      half8 hi, lo;
#pragma unroll
      for (int j = 0; j < 8; ++j) {
        _Float16 a = (_Float16)v[g][j];
        hi[j] = a;
        lo[j] = (_Float16)(v[g][j] - (float)a);
      }
      const int c = (g & 1) ? c1 : t;
      const int which = (g >> 1) * 2;  // 0 = X, 2 = H
      *(half8*)(ldsA + which * 4096 + c * 8) = hi;
      *(half8*)(ldsA + (which + 1) * 4096 + c * 8) = lo;
    }
  }
  __syncthreads();

  for (int kt = 0; kt < 16; ++kt) {
    const int cur = kt & 1;
    const _Float16* A = ldsA + cur * 16384;

    // --- issue next k-tile's fp32 loads EARLY (consumed after MFMAs) ---
    float v[4][8];
    if (kt < 15) {
      const int k0 = (kt + 1) * 32;
      *(float4*)&v[0][0] = *(const float4*)(px0 + k0);
      *(float4*)&v[0][4] = *(const float4*)(px0 + k0 + 4);
      *(float4*)&v[1][0] = *(const float4*)(px1 + k0);
      *(float4*)&v[1][4] = *(const float4*)(px1 + k0 + 4);
      *(float4*)&v[2][0] = *(const float4*)(ph0 + k0);
      *(float4*)&v[2][4] = *(const float4*)(ph0 + k0 + 4);
      *(float4*)&v[3][0] = *(const float4*)(ph1 + k0);
      *(float4*)&v[3][4] = *(const float4*)(ph1 + k0 + 4);
    }

    // --- A_hi fragments (reused across both jn) ---
    half8 axh[4], ahh[4];
#pragma unroll
    for (int i = 0; i < 4; ++i) {
      const int ao = ((wm * 4 + i) * 64 + lane) * 8;
      axh[i] = *(const half8*)(A + 0 * 4096 + ao);
      ahh[i] = *(const half8*)(A + 2 * 4096 + ao);
    }

    // --- compute: 144 MFMA / wave / k-step; W fragments direct from L2 ---
#pragma unroll
    for (int jn = 0; jn < 2; ++jn) {
      const int bo = (wn * 2 + jn) * 512 + lane * 8;
      const size_t tb = ((size_t)(nt * 16 + kt)) * 2048 + bo;
      half8 bh_ir = *(const half8*)(wperm + tb + 0 * WMAT_STRIDE);
      half8 bh_hr = *(const half8*)(wperm + tb + 1 * WMAT_STRIDE);
      half8 bh_iz = *(const half8*)(wperm + tb + 2 * WMAT_STRIDE);
      half8 bh_hz = *(const half8*)(wperm + tb + 3 * WMAT_STRIDE);
      half8 bh_in = *(const half8*)(wperm + tb + 4 * WMAT_STRIDE);
      half8 bh_hn = *(const half8*)(wperm + tb + 5 * WMAT_STRIDE);
      half8 bl_ir = *(const half8*)(wlo + tb + 0 * WMAT_STRIDE);
      half8 bl_hr = *(const half8*)(wlo + tb + 1 * WMAT_STRIDE);
      half8 bl_iz = *(const half8*)(wlo + tb + 2 * WMAT_STRIDE);
      half8 bl_hz = *(const half8*)(wlo + tb + 3 * WMAT_STRIDE);
      half8 bl_in = *(const half8*)(wlo + tb + 4 * WMAT_STRIDE);
      half8 bl_hn = *(const half8*)(wlo + tb + 5 * WMAT_STRIDE);
#pragma unroll
      for (int i = 0; i < 4; ++i) {
        const int ao = ((wm * 4 + i) * 64 + lane) * 8;
        half8 axl = *(const half8*)(A + 1 * 4096 + ao);
        half8 ahl = *(const half8*)(A + 3 * 4096 + ao);
        acc_r[i][jn]  = __builtin_amdgcn_mfma_f32_16x16x32_f16(axh[i], bh_ir, acc_r[i][jn], 0, 0, 0);
        acc_r[i][jn]  = __builtin_amdgcn_mfma_f32_16x16x32_f16(axl,    bh_ir, acc_r[i][jn], 0, 0, 0);
        acc_r[i][jn]  = __builtin_amdgcn_mfma_f32_16x16x32_f16(axh[i], bl_ir, acc_r[i][jn], 0, 0, 0);
        acc_r[i][jn]  = __builtin_amdgcn_mfma_f32_16x16x32_f16(ahh[i], bh_hr, acc_r[i][jn], 0, 0, 0);
        acc_r[i][jn]  = __builtin_amdgcn_mfma_f32_16x16x32_f16(ahl,    bh_hr, acc_r[i][jn], 0, 0, 0);
        acc_r[i][jn]  = __builtin_amdgcn_mfma_f32_16x16x32_f16(ahh[i], bl_hr, acc_r[i][jn], 0, 0, 0);
        acc_z[i][jn]  = __builtin_amdgcn_mfma_f32_16x16x32_f16(axh[i], bh_iz, acc_z[i][jn], 0, 0, 0);
        acc_z[i][jn]  = __builtin_amdgcn_mfma_f32_16x16x32_f16(axl,    bh_iz, acc_z[i][jn], 0, 0, 0);
        acc_z[i][jn]  = __builtin_amdgcn_mfma_f32_16x16x32_f16(axh[i], bl_iz, acc_z[i][jn], 0, 0, 0);
        acc_z[i][jn]  = __builtin_amdgcn_mfma_f32_16x16x32_f16(ahh[i], bh_hz, acc_z[i][jn], 0, 0, 0);
        acc_z[i][jn]  = __builtin_amdgcn_mfma_f32_16x16x32_f16(ahl,    bh_hz, acc_z[i][jn], 0, 0, 0);
        acc_z[i][jn]  = __builtin_amdgcn_mfma_f32_16x16x32_f16(ahh[i], bl_hz, acc_z[i][jn], 0, 0, 0);
        acc_in[i][jn] = __builtin_amdgcn_mfma_f32_16x16x32_f16(axh[i], bh_in, acc_in[i][jn], 0, 0, 0);
        acc_in[i][jn] = __builtin_amdgcn_mfma_f32_16x16x32_f16(axl,    bh_in, acc_in[i][jn], 0, 0, 0);
        acc_in[i][jn] = __builtin_amdgcn_mfma_f32_16x16x32_f16(axh[i], bl_in, acc_in[i][jn], 0, 0, 0);
        acc_hn[i][jn] = __builtin_amdgcn_mfma_f32_16x16x32_f16(ahh[i], bh_hn, acc_hn[i][jn], 0, 0, 0);
        acc_hn[i][jn] = __builtin_amdgcn_mfma_f32_16x16x32_f16(ahl,    bh_hn, acc_hn[i][jn], 0, 0, 0);
        acc_hn[i][jn] = __builtin_amdgcn_mfma_f32_16x16x32_f16(ahh[i], bl_hn, acc_hn[i][jn], 0, 0, 0);
      }
    }

    // --- split + write next tile into the other buffer (after MFMAs) ---
    if (kt < 15) {
      _Float16* base = ldsA + (cur ^ 1) * 16384;
#pragma unroll
      for (int g = 0; g < 4; ++g) {
        half8 hi, lo;
#pragma unroll
        for (int j = 0; j < 8; ++j) {
          _Float16 a = (_Float16)v[g][j];
          hi[j] = a;
          lo[j] = (_Float16)(v[g][j] - (float)a);
        }
        const int c = (g & 1) ? c1 : t;
        const int which = (g >> 1) * 2;
        *(half8*)(base + which * 4096 + c * 8) = hi;
        *(half8*)(base + (which + 1) * 4096 + c * 8) = lo;
      }
    }
    __syncthreads();  // buf[cur] fully consumed; buf[cur^1] fully written
  }

  // --- epilogue: gates + h_new. C/D layout: col = lane&15, row = quad*4+reg ---
  const int quad = lane >> 4;
  const int col = lane & 15;
#pragma unroll
  for (int i = 0; i < 4; ++i) {
    const int mbase = m0 + wm * 64 + i * 16 + quad * 4;
#pragma unroll
    for (int jn = 0; jn < 2; ++jn) {
      const int n = n0 + wn * 32 + jn * 16 + col;
      const float vbr = br[n], vbz = bz[n], vbn = bn[n];
#pragma unroll
      for (int r = 0; r < 4; ++r) {
        const int m = mbase + r;
        const float gr = acc_r[i][jn][r] + vbr;
        const float gz = acc_z[i][jn][r] + vbz;
        const float rg = 1.0f / (1.0f + __expf(-gr));
        const float zg = 1.0f / (1.0f + __expf(-gz));
        const float gn = acc_in[i][jn][r] + rg * acc_hn[i][jn][r] + vbn;
        const float e2 = __expf(2.0f * gn);          // inf-safe: tanh->+/-1
        const float ntv = 1.0f - 2.0f / (e2 + 1.0f);
        const float hp = h[m * 512 + n];
        out[m * 512 + n] = (1.0f - zg) * ntv + zg * hp;
      }
    }
  }
}

extern "C" void kernel_launch(void* const* d_in, const int* in_sizes, int n_in,
                              void* d_out, int out_size, void* d_ws, size_t ws_size,
                              hipStream_t stream) {
  const float* x   = (const float*)d_in[0];
  const float* h   = (const float*)d_in[1];
  const float* Wir = (const float*)d_in[2];
  const float* Whr = (const float*)d_in[3];
  const float* br  = (const float*)d_in[4];
  const float* Wiz = (const float*)d_in[5];
  const float* Whz = (const float*)d_in[6];
  const float* bz  = (const float*)d_in[7];
  const float* Win = (const float*)d_in[8];
  const float* Whn = (const float*)d_in[9];
  const float* bn  = (const float*)d_in[10];
  float* out = (float*)d_out;
  _Float16* wperm = (_Float16*)d_ws;  // needs 2 * 6*512*512*2 = 6.3 MB

  permute_w<<<768, 256, 0, stream>>>(Wir, Whr, Wiz, Whz, Win, Whn, wperm);
  gru_fused<<<1024, 256, 0, stream>>>(x, h, wperm, br, bz, bn, out);
}

// Round 2
// 275.296 us; speedup vs baseline: 1.0945x; 1.0945x over previous
//
#include <hip/hip_runtime.h>
#include <hip/hip_fp16.h>

typedef _Float16 half8 __attribute__((ext_vector_type(8)));
typedef float floatx4 __attribute__((ext_vector_type(4)));

// wperm layout: hi part at [0, 6*512*512), lo part at [WLO_OFF, 2*WLO_OFF)
#define WLO_OFF (6 * 512 * 512)
#define WMAT_STRIDE ((size_t)(8 * 16 * 2048))  // halfs per W matrix in wperm

// ---------------------------------------------------------------------------
// P1: convert 6 W matrices [512(k) x 512(n)] fp32 -> fp16 hi + fp16 lo
// (lo = fp16(W - float(hi)), ~22-bit effective mantissa), laid out in MFMA
// B-operand fragment order: tile(w, nt, ki) is 4096B; within tile, chunk
// (u, l) at u*1024 + l*16 holds B[k0 + 8*(l>>4) + j][n0 + 16*u + (l&15)],
// j = 0..7 contiguous.
// ---------------------------------------------------------------------------
__global__ __launch_bounds__(256) void permute_w(
    const float* __restrict__ Wir, const float* __restrict__ Whr,
    const float* __restrict__ Wiz, const float* __restrict__ Whz,
    const float* __restrict__ Win, const float* __restrict__ Whn,
    _Float16* __restrict__ wperm) {
  __shared__ __align__(16) float tile[32 * 68];  // padded rows
  const int b = blockIdx.x;
  const int w = b >> 7;         // 0..5
  const int rem = b & 127;
  const int ki = rem >> 3;      // 0..15 (k-tile)
  const int nt = rem & 7;       // 0..7  (n-tile of 64)
  const float* W = (w == 0) ? Wir : (w == 1) ? Whr : (w == 2) ? Wiz
                 : (w == 3) ? Whz : (w == 4) ? Win : Whn;
  const int k0 = ki * 32, n0 = nt * 64;
  const int t = threadIdx.x;

  // coalesced read: thread t reads W[k0 + (t>>3)][n0 + (t&7)*8 .. +7]
  const int kk = t >> 3;
  const int nn = (t & 7) * 8;
  const float* src = W + (k0 + kk) * 512 + n0 + nn;
  float4 f0 = *(const float4*)(src);
  float4 f1 = *(const float4*)(src + 4);
  float* drow = tile + kk * 68 + nn;
  *(float4*)(drow) = f0;
  *(float4*)(drow + 4) = f1;
  __syncthreads();

  // gather fragment chunk c = t: u = t>>6, l = t&63
  const int u = t >> 6, l = t & 63;
  const int nloc = 16 * u + (l & 15);
  const int kbase = 8 * (l >> 4);
  half8 vh, vl;
#pragma unroll
  for (int j = 0; j < 8; ++j) {
    float f = tile[(kbase + j) * 68 + nloc];
    _Float16 hi = (_Float16)f;
    _Float16 lo = (_Float16)(f - (float)hi);
    vh[j] = hi;
    vl[j] = lo;
  }
  const size_t off = ((size_t)((w * 8 + nt) * 16 + ki)) * 2048 + t * 8;
  *(half8*)(wperm + off) = vh;
  *(half8*)(wperm + WLO_OFF + off) = vl;
}

// ---------------------------------------------------------------------------
// Fused GRU with fp16 hi/lo emulated-fp32 MFMA:
//   a*b ~= a_hi*b_hi + a_lo*b_hi + a_hi*b_lo   (residual ~2^-22)
//
// This round: block tile 64(m) x 64(n), 4 waves each owning 64x16 (wn = wave
// id picks the 16-col group). Accumulators halve to 64 regs/wave and A-LDS
// halves to 32 KB -> register AND LDS occupancy limits relax together
// (target ~10 waves/CU vs previous 8). Single barrier per k-step, double-
// buffered A staging, W hi+lo fragments direct from L2 (786 KB per XCD,
// pinned by nt = bid&7 swizzle). s_setprio(1) around the MFMA cluster.
// ---------------------------------------------------------------------------
__global__ __launch_bounds__(256, 2) void gru_fused(
    const float* __restrict__ x, const float* __restrict__ h,
    const _Float16* __restrict__ wperm,
    const float* __restrict__ br, const float* __restrict__ bz,
    const float* __restrict__ bn, float* __restrict__ out) {
  // 32 KB double-buffered A staging: [buf][Xh|Xl|Hh|Hl][2048 halfs]
  __shared__ __align__(16) _Float16 ldsA[2 * 4 * 2048];

  const int t = threadIdx.x;
  const int lane = t & 63;
  const int wn = t >> 6;    // 0..3: 16-col group of this wave
  const int bid = blockIdx.x;
  const int nt = bid & 7;   // n-tile -> round-robin XCD pinning for W L2 locality
  const int mt = bid >> 3;
  const int m0 = mt * 64;
  const int n0 = nt * 64;
  const _Float16* wlo = wperm + WLO_OFF;

  floatx4 acc_r[4] = {};
  floatx4 acc_z[4] = {};
  floatx4 acc_in[4] = {};
  floatx4 acc_hn[4] = {};

  // staging chunk c = t: row m = 16*(c>>6) + (c&15), k offset = 8*((c>>4)&3).
  const int mA = 16 * (t >> 6) + (t & 15);
  const int kA = 8 * ((t >> 4) & 3);
  const float* px = x + (m0 + mA) * 512 + kA;
  const float* ph = h + (m0 + mA) * 512 + kA;

  // ---- prologue: stage k-tile 0 into buffer 0 ----
  {
    float v[2][8];
    *(float4*)&v[0][0] = *(const float4*)(px);
    *(float4*)&v[0][4] = *(const float4*)(px + 4);
    *(float4*)&v[1][0] = *(const float4*)(ph);
    *(float4*)&v[1][4] = *(const float4*)(ph + 4);
#pragma unroll
    for (int g = 0; g < 2; ++g) {
      half8 hi, lo;
#pragma unroll
      for (int j = 0; j < 8; ++j) {
        _Float16 a = (_Float16)v[g][j];
        hi[j] = a;
        lo[j] = (_Float16)(v[g][j] - (float)a);
      }
      *(half8*)(ldsA + (g * 2 + 0) * 2048 + t * 8) = hi;  // Xh / Hh
      *(half8*)(ldsA + (g * 2 + 1) * 2048 + t * 8) = lo;  // Xl / Hl
    }
  }
  __syncthreads();

  for (int kt = 0; kt < 16; ++kt) {
    const _Float16* A = ldsA + (kt & 1) * 8192;

    // --- issue next k-tile's fp32 loads EARLY (consumed after MFMAs) ---
    float v[2][8];
    if (kt < 15) {
      const int k0 = (kt + 1) * 32;
      *(float4*)&v[0][0] = *(const float4*)(px + k0);
      *(float4*)&v[0][4] = *(const float4*)(px + k0 + 4);
      *(float4*)&v[1][0] = *(const float4*)(ph + k0);
      *(float4*)&v[1][4] = *(const float4*)(ph + k0 + 4);
    }

    // --- W fragments direct from L2 (12 x 16B/lane, coalesced) ---
    const size_t tb = ((size_t)(nt * 16 + kt)) * 2048 + wn * 512 + lane * 8;
    half8 bh_ir = *(const half8*)(wperm + tb + 0 * WMAT_STRIDE);
    half8 bh_hr = *(const half8*)(wperm + tb + 1 * WMAT_STRIDE);
    half8 bh_iz = *(const half8*)(wperm + tb + 2 * WMAT_STRIDE);
    half8 bh_hz = *(const half8*)(wperm + tb + 3 * WMAT_STRIDE);
    half8 bh_in = *(const half8*)(wperm + tb + 4 * WMAT_STRIDE);
    half8 bh_hn = *(const half8*)(wperm + tb + 5 * WMAT_STRIDE);
    half8 bl_ir = *(const half8*)(wlo + tb + 0 * WMAT_STRIDE);
    half8 bl_hr = *(const half8*)(wlo + tb + 1 * WMAT_STRIDE);
    half8 bl_iz = *(const half8*)(wlo + tb + 2 * WMAT_STRIDE);
    half8 bl_hz = *(const half8*)(wlo + tb + 3 * WMAT_STRIDE);
    half8 bl_in = *(const half8*)(wlo + tb + 4 * WMAT_STRIDE);
    half8 bl_hn = *(const half8*)(wlo + tb + 5 * WMAT_STRIDE);

    // --- A_hi fragments (each used 3x below) ---
    half8 axh[4], ahh[4];
#pragma unroll
    for (int i = 0; i < 4; ++i) {
      const int ao = (i * 64 + lane) * 8;
      axh[i] = *(const half8*)(A + 0 * 2048 + ao);  // Xh
      ahh[i] = *(const half8*)(A + 2 * 2048 + ao);  // Hh
    }

    __builtin_amdgcn_s_setprio(1);
#pragma unroll
    for (int i = 0; i < 4; ++i) {
      const int ao = (i * 64 + lane) * 8;
      half8 axl = *(const half8*)(A + 1 * 2048 + ao);  // Xl
      half8 ahl = *(const half8*)(A + 3 * 2048 + ao);  // Hl
      acc_r[i]  = __builtin_amdgcn_mfma_f32_16x16x32_f16(axh[i], bh_ir, acc_r[i], 0, 0, 0);
      acc_r[i]  = __builtin_amdgcn_mfma_f32_16x16x32_f16(axl,    bh_ir, acc_r[i], 0, 0, 0);
      acc_r[i]  = __builtin_amdgcn_mfma_f32_16x16x32_f16(axh[i], bl_ir, acc_r[i], 0, 0, 0);
      acc_r[i]  = __builtin_amdgcn_mfma_f32_16x16x32_f16(ahh[i], bh_hr, acc_r[i], 0, 0, 0);
      acc_r[i]  = __builtin_amdgcn_mfma_f32_16x16x32_f16(ahl,    bh_hr, acc_r[i], 0, 0, 0);
      acc_r[i]  = __builtin_amdgcn_mfma_f32_16x16x32_f16(ahh[i], bl_hr, acc_r[i], 0, 0, 0);
      acc_z[i]  = __builtin_amdgcn_mfma_f32_16x16x32_f16(axh[i], bh_iz, acc_z[i], 0, 0, 0);
      acc_z[i]  = __builtin_amdgcn_mfma_f32_16x16x32_f16(axl,    bh_iz, acc_z[i], 0, 0, 0);
      acc_z[i]  = __builtin_amdgcn_mfma_f32_16x16x32_f16(axh[i], bl_iz, acc_z[i], 0, 0, 0);
      acc_z[i]  = __builtin_amdgcn_mfma_f32_16x16x32_f16(ahh[i], bh_hz, acc_z[i], 0, 0, 0);
      acc_z[i]  = __builtin_amdgcn_mfma_f32_16x16x32_f16(ahl,    bh_hz, acc_z[i], 0, 0, 0);
      acc_z[i]  = __builtin_amdgcn_mfma_f32_16x16x32_f16(ahh[i], bl_hz, acc_z[i], 0, 0, 0);
      acc_in[i] = __builtin_amdgcn_mfma_f32_16x16x32_f16(axh[i], bh_in, acc_in[i], 0, 0, 0);
      acc_in[i] = __builtin_amdgcn_mfma_f32_16x16x32_f16(axl,    bh_in, acc_in[i], 0, 0, 0);
      acc_in[i] = __builtin_amdgcn_mfma_f32_16x16x32_f16(axh[i], bl_in, acc_in[i], 0, 0, 0);
      acc_hn[i] = __builtin_amdgcn_mfma_f32_16x16x32_f16(ahh[i], bh_hn, acc_hn[i], 0, 0, 0);
      acc_hn[i] = __builtin_amdgcn_mfma_f32_16x16x32_f16(ahl,    bh_hn, acc_hn[i], 0, 0, 0);
      acc_hn[i] = __builtin_amdgcn_mfma_f32_16x16x32_f16(ahh[i], bl_hn, acc_hn[i], 0, 0, 0);
    }
    __builtin_amdgcn_s_setprio(0);

    // --- split + write next tile into the other buffer (after MFMAs) ---
    if (kt < 15) {
      _Float16* base = ldsA + ((kt & 1) ^ 1) * 8192;
#pragma unroll
      for (int g = 0; g < 2; ++g) {
        half8 hi, lo;
#pragma unroll
        for (int j = 0; j < 8; ++j) {
          _Float16 a = (_Float16)v[g][j];
          hi[j] = a;
          lo[j] = (_Float16)(v[g][j] - (float)a);
        }
        *(half8*)(base + (g * 2 + 0) * 2048 + t * 8) = hi;
        *(half8*)(base + (g * 2 + 1) * 2048 + t * 8) = lo;
      }
    }
    __syncthreads();  // buf[cur] fully consumed; buf[cur^1] fully written
  }

  // --- epilogue: gates + h_new. C/D layout: col = lane&15, row = quad*4+reg ---
  const int quad = lane >> 4;
  const int col = lane & 15;
  const int n = n0 + wn * 16 + col;
  const float vbr = br[n], vbz = bz[n], vbn = bn[n];
#pragma unroll
  for (int i = 0; i < 4; ++i) {
    const int mbase = m0 + i * 16 + quad * 4;
#pragma unroll
    for (int r = 0; r < 4; ++r) {
      const int m = mbase + r;
      const float gr = acc_r[i][r] + vbr;
      const float gz = acc_z[i][r] + vbz;
      const float rg = 1.0f / (1.0f + __expf(-gr));
      const float zg = 1.0f / (1.0f + __expf(-gz));
      const float gn = acc_in[i][r] + rg * acc_hn[i][r] + vbn;
      const float e2 = __expf(2.0f * gn);          // inf-safe: tanh->+/-1
      const float ntv = 1.0f - 2.0f / (e2 + 1.0f);
      const float hp = h[m * 512 + n];
      out[m * 512 + n] = (1.0f - zg) * ntv + zg * hp;
    }
  }
}

extern "C" void kernel_launch(void* const* d_in, const int* in_sizes, int n_in,
                              void* d_out, int out_size, void* d_ws, size_t ws_size,
                              hipStream_t stream) {
  const float* x   = (const float*)d_in[0];
  const float* h   = (const float*)d_in[1];
  const float* Wir = (const float*)d_in[2];
  const float* Whr = (const float*)d_in[3];
  const float* br  = (const float*)d_in[4];
  const float* Wiz = (const float*)d_in[5];
  const float* Whz = (const float*)d_in[6];
  const float* bz  = (const float*)d_in[7];
  const float* Win = (const float*)d_in[8];
  const float* Whn = (const float*)d_in[9];
  const float* bn  = (const float*)d_in[10];
  float* out = (float*)d_out;
  _Float16* wperm = (_Float16*)d_ws;  // needs 2 * 6*512*512*2 = 6.3 MB

  permute_w<<<768, 256, 0, stream>>>(Wir, Whr, Wiz, Whz, Win, Whn, wperm);
  gru_fused<<<2048, 256, 0, stream>>>(x, h, wperm, br, bz, bn, out);
}

// Round 3
// 251.780 us; speedup vs baseline: 1.1967x; 1.0934x over previous
//
#include <hip/hip_runtime.h>
#include <hip/hip_fp16.h>

typedef _Float16 half8 __attribute__((ext_vector_type(8)));
typedef float floatx4 __attribute__((ext_vector_type(4)));

// wperm layout: hi part at [0, 6*512*512), lo part at [WLO_OFF, 2*WLO_OFF)
#define WLO_OFF (6 * 512 * 512)
#define WMAT_STRIDE ((size_t)(8 * 16 * 2048))  // halfs per W matrix in wperm

// ---------------------------------------------------------------------------
// P1: convert 6 W matrices [512(k) x 512(n)] fp32 -> fp16 hi + fp16 lo
// (lo = fp16(W - float(hi)), ~22-bit effective mantissa), laid out in MFMA
// B-operand fragment order: tile(w, nt, ki) is 4096B; within tile, chunk
// (u, l) at u*1024 + l*16 holds B[k0 + 8*(l>>4) + j][n0 + 16*u + (l&15)],
// j = 0..7 contiguous.
// ---------------------------------------------------------------------------
__global__ __launch_bounds__(256) void permute_w(
    const float* __restrict__ Wir, const float* __restrict__ Whr,
    const float* __restrict__ Wiz, const float* __restrict__ Whz,
    const float* __restrict__ Win, const float* __restrict__ Whn,
    _Float16* __restrict__ wperm) {
  __shared__ __align__(16) float tile[32 * 68];  // padded rows
  const int b = blockIdx.x;
  const int w = b >> 7;         // 0..5
  const int rem = b & 127;
  const int ki = rem >> 3;      // 0..15 (k-tile)
  const int nt = rem & 7;       // 0..7  (n-tile of 64)
  const float* W = (w == 0) ? Wir : (w == 1) ? Whr : (w == 2) ? Wiz
                 : (w == 3) ? Whz : (w == 4) ? Win : Whn;
  const int k0 = ki * 32, n0 = nt * 64;
  const int t = threadIdx.x;

  // coalesced read: thread t reads W[k0 + (t>>3)][n0 + (t&7)*8 .. +7]
  const int kk = t >> 3;
  const int nn = (t & 7) * 8;
  const float* src = W + (k0 + kk) * 512 + n0 + nn;
  float4 f0 = *(const float4*)(src);
  float4 f1 = *(const float4*)(src + 4);
  float* drow = tile + kk * 68 + nn;
  *(float4*)(drow) = f0;
  *(float4*)(drow + 4) = f1;
  __syncthreads();

  // gather fragment chunk c = t: u = t>>6, l = t&63
  const int u = t >> 6, l = t & 63;
  const int nloc = 16 * u + (l & 15);
  const int kbase = 8 * (l >> 4);
  half8 vh, vl;
#pragma unroll
  for (int j = 0; j < 8; ++j) {
    float f = tile[(kbase + j) * 68 + nloc];
    _Float16 hi = (_Float16)f;
    _Float16 lo = (_Float16)(f - (float)hi);
    vh[j] = hi;
    vl[j] = lo;
  }
  const size_t off = ((size_t)((w * 8 + nt) * 16 + ki)) * 2048 + t * 8;
  *(half8*)(wperm + off) = vh;
  *(half8*)(wperm + WLO_OFF + off) = vl;
}

// ---------------------------------------------------------------------------
// Fused GRU with fp16 hi/lo emulated-fp32 MFMA:
//   a*b ~= a_hi*b_hi + a_lo*b_hi + a_hi*b_lo   (residual ~2^-22)
//
// This round: block tile 128(m) x 64(n), 4 waves each owning 128x16.
//   - W per wave per k-step (12 KB) now feeds 144 MFMAs (was 72): W L2
//     traffic halves and the burst covers load latency 2x better.
//   - LOAD ORDER FIX: W loads (L2-hit) issued BEFORE A-prefetch (L3/HBM
//     latency). vmcnt is FIFO, so the MFMA burst now only waits for W
//     (vmcnt(8) graduated), and A latency hides under the burst until the
//     post-MFMA split phase. sched_barrier(0) pins the issue order.
//   - single barrier per k-step, double-buffered A LDS (64 KB).
// ---------------------------------------------------------------------------
__global__ __launch_bounds__(256, 2) void gru_fused(
    const float* __restrict__ x, const float* __restrict__ h,
    const _Float16* __restrict__ wperm,
    const float* __restrict__ br, const float* __restrict__ bz,
    const float* __restrict__ bn, float* __restrict__ out) {
  // 64 KB double-buffered A staging: [buf][Xh|Xl|Hh|Hl][4096 halfs]
  __shared__ __align__(16) _Float16 ldsA[2 * 4 * 4096];

  const int t = threadIdx.x;
  const int lane = t & 63;
  const int wn = t >> 6;    // 0..3: 16-col group of this wave
  const int bid = blockIdx.x;
  const int nt = bid & 7;   // n-tile -> round-robin XCD pinning for W L2 locality
  const int mt = bid >> 3;  // 0..127
  const int m0 = mt * 128;
  const int n0 = nt * 64;
  const _Float16* wlo = wperm + WLO_OFF;

  floatx4 acc_r[8] = {};
  floatx4 acc_z[8] = {};
  floatx4 acc_in[8] = {};
  floatx4 acc_hn[8] = {};

  // staging chunks: c0 = t (rows 0..63), c1 = t+256 (rows 64..127);
  // row m = 16*(c>>6) + (c&15), k offset = 8*((c>>4)&3).
  const int mA = 16 * (t >> 6) + (t & 15);
  const int kA = 8 * ((t >> 4) & 3);
  const float* px0 = x + (m0 + mA) * 512 + kA;
  const float* ph0 = h + (m0 + mA) * 512 + kA;
  const float* px1 = px0 + 64 * 512;
  const float* ph1 = ph0 + 64 * 512;
  const int c0 = t, c1 = t + 256;

  // ---- prologue: stage k-tile 0 into buffer 0 ----
  {
    float v[4][8];
    *(float4*)&v[0][0] = *(const float4*)(px0);
    *(float4*)&v[0][4] = *(const float4*)(px0 + 4);
    *(float4*)&v[1][0] = *(const float4*)(px1);
    *(float4*)&v[1][4] = *(const float4*)(px1 + 4);
    *(float4*)&v[2][0] = *(const float4*)(ph0);
    *(float4*)&v[2][4] = *(const float4*)(ph0 + 4);
    *(float4*)&v[3][0] = *(const float4*)(ph1);
    *(float4*)&v[3][4] = *(const float4*)(ph1 + 4);
#pragma unroll
    for (int g = 0; g < 4; ++g) {
      half8 hi, lo;
#pragma unroll
      for (int j = 0; j < 8; ++j) {
        _Float16 a = (_Float16)v[g][j];
        hi[j] = a;
        lo[j] = (_Float16)(v[g][j] - (float)a);
      }
      const int c = (g & 1) ? c1 : c0;
      const int part = (g >> 1) * 2;  // 0 = X, 2 = H
      *(half8*)(ldsA + (part + 0) * 4096 + c * 8) = hi;
      *(half8*)(ldsA + (part + 1) * 4096 + c * 8) = lo;
    }
  }
  __syncthreads();

  for (int kt = 0; kt < 16; ++kt) {
    const _Float16* A = ldsA + (kt & 1) * 16384;

    // --- 1) W fragments FIRST (L2-hit, 12 x 16B/lane, coalesced) ---
    const size_t tb = ((size_t)(nt * 16 + kt)) * 2048 + wn * 512 + lane * 8;
    half8 bh_ir = *(const half8*)(wperm + tb + 0 * WMAT_STRIDE);
    half8 bh_hr = *(const half8*)(wperm + tb + 1 * WMAT_STRIDE);
    half8 bh_iz = *(const half8*)(wperm + tb + 2 * WMAT_STRIDE);
    half8 bh_hz = *(const half8*)(wperm + tb + 3 * WMAT_STRIDE);
    half8 bh_in = *(const half8*)(wperm + tb + 4 * WMAT_STRIDE);
    half8 bh_hn = *(const half8*)(wperm + tb + 5 * WMAT_STRIDE);
    half8 bl_ir = *(const half8*)(wlo + tb + 0 * WMAT_STRIDE);
    half8 bl_hr = *(const half8*)(wlo + tb + 1 * WMAT_STRIDE);
    half8 bl_iz = *(const half8*)(wlo + tb + 2 * WMAT_STRIDE);
    half8 bl_hz = *(const half8*)(wlo + tb + 3 * WMAT_STRIDE);
    half8 bl_in = *(const half8*)(wlo + tb + 4 * WMAT_STRIDE);
    half8 bl_hn = *(const half8*)(wlo + tb + 5 * WMAT_STRIDE);
    __builtin_amdgcn_sched_barrier(0);  // W loads issue before anything below

    // --- 2) A-prefetch for kt+1 (slow L3/HBM; consumed after MFMAs) ---
    float v[4][8];
    if (kt < 15) {
      const int k0 = (kt + 1) * 32;
      *(float4*)&v[0][0] = *(const float4*)(px0 + k0);
      *(float4*)&v[0][4] = *(const float4*)(px0 + k0 + 4);
      *(float4*)&v[1][0] = *(const float4*)(px1 + k0);
      *(float4*)&v[1][4] = *(const float4*)(px1 + k0 + 4);
      *(float4*)&v[2][0] = *(const float4*)(ph0 + k0);
      *(float4*)&v[2][4] = *(const float4*)(ph0 + k0 + 4);
      *(float4*)&v[3][0] = *(const float4*)(ph1 + k0);
      *(float4*)&v[3][4] = *(const float4*)(ph1 + k0 + 4);
    }
    __builtin_amdgcn_sched_barrier(0);  // A loads issue before MFMA region

    // --- 3) compute: 144 MFMA / wave / k-step, A frags per-i from LDS ---
    __builtin_amdgcn_s_setprio(1);
#pragma unroll
    for (int i = 0; i < 8; ++i) {
      const int ao = (i * 64 + lane) * 8;
      half8 axh = *(const half8*)(A + 0 * 4096 + ao);
      half8 axl = *(const half8*)(A + 1 * 4096 + ao);
      half8 ahh = *(const half8*)(A + 2 * 4096 + ao);
      half8 ahl = *(const half8*)(A + 3 * 4096 + ao);
      // hi*hi first (oldest loads), then lo*hi, then hi*lo (newest loads)
      acc_r[i]  = __builtin_amdgcn_mfma_f32_16x16x32_f16(axh, bh_ir, acc_r[i], 0, 0, 0);
      acc_r[i]  = __builtin_amdgcn_mfma_f32_16x16x32_f16(ahh, bh_hr, acc_r[i], 0, 0, 0);
      acc_z[i]  = __builtin_amdgcn_mfma_f32_16x16x32_f16(axh, bh_iz, acc_z[i], 0, 0, 0);
      acc_z[i]  = __builtin_amdgcn_mfma_f32_16x16x32_f16(ahh, bh_hz, acc_z[i], 0, 0, 0);
      acc_in[i] = __builtin_amdgcn_mfma_f32_16x16x32_f16(axh, bh_in, acc_in[i], 0, 0, 0);
      acc_hn[i] = __builtin_amdgcn_mfma_f32_16x16x32_f16(ahh, bh_hn, acc_hn[i], 0, 0, 0);
      acc_r[i]  = __builtin_amdgcn_mfma_f32_16x16x32_f16(axl, bh_ir, acc_r[i], 0, 0, 0);
      acc_r[i]  = __builtin_amdgcn_mfma_f32_16x16x32_f16(ahl, bh_hr, acc_r[i], 0, 0, 0);
      acc_z[i]  = __builtin_amdgcn_mfma_f32_16x16x32_f16(axl, bh_iz, acc_z[i], 0, 0, 0);
      acc_z[i]  = __builtin_amdgcn_mfma_f32_16x16x32_f16(ahl, bh_hz, acc_z[i], 0, 0, 0);
      acc_in[i] = __builtin_amdgcn_mfma_f32_16x16x32_f16(axl, bh_in, acc_in[i], 0, 0, 0);
      acc_hn[i] = __builtin_amdgcn_mfma_f32_16x16x32_f16(ahl, bh_hn, acc_hn[i], 0, 0, 0);
      acc_r[i]  = __builtin_amdgcn_mfma_f32_16x16x32_f16(axh, bl_ir, acc_r[i], 0, 0, 0);
      acc_r[i]  = __builtin_amdgcn_mfma_f32_16x16x32_f16(ahh, bl_hr, acc_r[i], 0, 0, 0);
      acc_z[i]  = __builtin_amdgcn_mfma_f32_16x16x32_f16(axh, bl_iz, acc_z[i], 0, 0, 0);
      acc_z[i]  = __builtin_amdgcn_mfma_f32_16x16x32_f16(ahh, bl_hz, acc_z[i], 0, 0, 0);
      acc_in[i] = __builtin_amdgcn_mfma_f32_16x16x32_f16(axh, bl_in, acc_in[i], 0, 0, 0);
      acc_hn[i] = __builtin_amdgcn_mfma_f32_16x16x32_f16(ahh, bl_hn, acc_hn[i], 0, 0, 0);
    }
    __builtin_amdgcn_s_setprio(0);

    // --- 4) split + write next tile into the other buffer (after MFMAs) ---
    if (kt < 15) {
      _Float16* base = ldsA + ((kt & 1) ^ 1) * 16384;
#pragma unroll
      for (int g = 0; g < 4; ++g) {
        half8 hi, lo;
#pragma unroll
        for (int j = 0; j < 8; ++j) {
          _Float16 a = (_Float16)v[g][j];
          hi[j] = a;
          lo[j] = (_Float16)(v[g][j] - (float)a);
        }
        const int c = (g & 1) ? c1 : c0;
        const int part = (g >> 1) * 2;
        *(half8*)(base + (part + 0) * 4096 + c * 8) = hi;
        *(half8*)(base + (part + 1) * 4096 + c * 8) = lo;
      }
    }
    __syncthreads();  // buf[cur] fully consumed; buf[cur^1] fully written
  }

  // --- epilogue: gates + h_new. C/D layout: col = lane&15, row = quad*4+reg ---
  const int quad = lane >> 4;
  const int col = lane & 15;
  const int n = n0 + wn * 16 + col;
  const float vbr = br[n], vbz = bz[n], vbn = bn[n];
#pragma unroll
  for (int i = 0; i < 8; ++i) {
    const int mbase = m0 + i * 16 + quad * 4;
#pragma unroll
    for (int r = 0; r < 4; ++r) {
      const int m = mbase + r;
      const float gr = acc_r[i][r] + vbr;
      const float gz = acc_z[i][r] + vbz;
      const float rg = 1.0f / (1.0f + __expf(-gr));
      const float zg = 1.0f / (1.0f + __expf(-gz));
      const float gn = acc_in[i][r] + rg * acc_hn[i][r] + vbn;
      const float e2 = __expf(2.0f * gn);          // inf-safe: tanh->+/-1
      const float ntv = 1.0f - 2.0f / (e2 + 1.0f);
      const float hp = h[m * 512 + n];
      out[m * 512 + n] = (1.0f - zg) * ntv + zg * hp;
    }
  }
}

extern "C" void kernel_launch(void* const* d_in, const int* in_sizes, int n_in,
                              void* d_out, int out_size, void* d_ws, size_t ws_size,
                              hipStream_t stream) {
  const float* x   = (const float*)d_in[0];
  const float* h   = (const float*)d_in[1];
  const float* Wir = (const float*)d_in[2];
  const float* Whr = (const float*)d_in[3];
  const float* br  = (const float*)d_in[4];
  const float* Wiz = (const float*)d_in[5];
  const float* Whz = (const float*)d_in[6];
  const float* bz  = (const float*)d_in[7];
  const float* Win = (const float*)d_in[8];
  const float* Whn = (const float*)d_in[9];
  const float* bn  = (const float*)d_in[10];
  float* out = (float*)d_out;
  _Float16* wperm = (_Float16*)d_ws;  // needs 2 * 6*512*512*2 = 6.3 MB

  permute_w<<<768, 256, 0, stream>>>(Wir, Whr, Wiz, Whz, Win, Whn, wperm);
  gru_fused<<<1024, 256, 0, stream>>>(x, h, wperm, br, bz, bn, out);
}